// Round 1
// baseline (258.557 us; speedup 1.0000x reference)
//
#include <hip/hip_runtime.h>

// Problem constants (from setup_inputs): B=2, Hi=Wi=64, Di=32, C=16, F=8,
// strides (2,2,2), kernel 3x3x3, Ho=Wo=128, Do=64. Output [B,Ho,Wo,Do,F] f32.
constexpr int Bc  = 2;
constexpr int HiC = 64, WiC = 64, DiC = 32;
constexpr int Cc  = 16, Fc  = 8;
constexpr int HoC = 128, WoC = 128, DoC = 64;
constexpr int NW  = 27 * Fc * Cc;   // 3456 kernel weights

// Mapping: block = 256 threads = 4 waves; block covers 8 consecutive wo at one
// (b, ho). Each wave covers 2 SAME-PARITY columns (wo, wo+2) -> kh/kw validity
// is wave-uniform. Lane = (half: which column, rr: depth pair). Each lane owns
// do = 2*rr+q (dn even -> kd in {0,2}) and do = 2*rr+1-q (dn odd -> kd=1),
// where q = (bp+1)&1. The 3 kd taps are fully lane-dense, kd wave-uniform.
__global__ __launch_bounds__(256)
void sconv3dt_kernel(const float* __restrict__ images,
                     const int*   __restrict__ base_plane,
                     const float* __restrict__ kern,
                     float*       __restrict__ out) {
    __shared__ float wlds[NW];
    for (int i = threadIdx.x; i < NW; i += 256) wlds[i] = kern[i];
    __syncthreads();

    const int t    = threadIdx.x;
    const int wv   = t >> 6;        // wave in block: 0..3
    const int lane = t & 63;
    const int half = lane >> 5;     // which of the wave's 2 columns
    const int rr   = lane & 31;     // depth pair index
    const int b    = blockIdx.z;
    const int ho   = blockIdx.y;
    // waves cover wo offsets {0,2},{1,3},{4,6},{5,7} within the 8-wide tile
    const int wo   = (blockIdx.x << 3) + (wv & 1) + ((wv >> 1) << 2) + (half << 1);

    const int bp_col = base_plane[(b * HoC + ho) * WoC + wo];
    const int q   = (bp_col + 1) & 1;
    const int doE = 2 * rr + q;       // (bp+do+1) even -> kd in {0,2}
    const int doO = 2 * rr + 1 - q;   // (bp+do+1) odd  -> kd = 1

    float accE[Fc] = {0, 0, 0, 0, 0, 0, 0, 0};
    float accO[Fc] = {0, 0, 0, 0, 0, 0, 0, 0};

    #pragma unroll
    for (int kh = 0; kh < 3; ++kh) {
        const int hn = ho + 1 - kh;
        if ((hn & 1) || hn < 0 || hn >= HoC) continue;   // uniform per block
        const int hi = hn >> 1;
        #pragma unroll
        for (int kw = 0; kw < 3; ++kw) {
            const int wn = wo + 1 - kw;
            if (wn & 1) continue;                        // uniform per wave
            const bool wok = (wn >= 0) && (wn < WoC);    // per-lane only at edges
            int wi = wn >> 1;
            wi = wi < 0 ? 0 : (wi > WiC - 1 ? WiC - 1 : wi);
            // bp_in[b,hi,wi] = base_plane[b, 2*hi, 2*wi] >> 1 (floor div, vals >= 0)
            const int bpg = base_plane[(b * HoC + 2 * hi) * WoC + 2 * wi] >> 1;
            const float* ibase =
                images + (size_t)((b * HiC + hi) * WiC + wi) * (DiC * Cc);
            const int kbase = (kh * 3 + kw) * 3;

            auto tap = [&](int dd, int kd, float* acc) {
                const int dn = bp_col + dd + 1 - kd;     // even by construction
                const int di = (dn >> 1) - bpg;
                const bool ok = wok && (di >= 0) && (di < DiC);
                float4 v0 = make_float4(0.f, 0.f, 0.f, 0.f);
                float4 v1 = v0, v2 = v0, v3 = v0;
                if (ok) {
                    const float4* ip = (const float4*)(ibase + (size_t)di * Cc);
                    v0 = ip[0]; v1 = ip[1]; v2 = ip[2]; v3 = ip[3];
                }
                const float4* wp = (const float4*)(wlds + (kbase + kd) * (Fc * Cc));
                #pragma unroll
                for (int f = 0; f < Fc; ++f) {
                    // uniform-address LDS reads -> broadcast, conflict-free
                    float4 w0 = wp[4 * f + 0];
                    float4 w1 = wp[4 * f + 1];
                    float4 w2 = wp[4 * f + 2];
                    float4 w3 = wp[4 * f + 3];
                    acc[f] += v0.x * w0.x + v0.y * w0.y + v0.z * w0.z + v0.w * w0.w
                            + v1.x * w1.x + v1.y * w1.y + v1.z * w1.z + v1.w * w1.w
                            + v2.x * w2.x + v2.y * w2.y + v2.z * w2.z + v2.w * w2.w
                            + v3.x * w3.x + v3.y * w3.y + v3.z * w3.z + v3.w * w3.w;
                }
            };
            tap(doE, 0, accE);
            tap(doE, 2, accE);
            tap(doO, 1, accO);
        }
    }

    float* op = out + (size_t)((b * HoC + ho) * WoC + wo) * (DoC * Fc);
    float4* oE = (float4*)(op + doE * Fc);
    oE[0] = make_float4(accE[0], accE[1], accE[2], accE[3]);
    oE[1] = make_float4(accE[4], accE[5], accE[6], accE[7]);
    float4* oO = (float4*)(op + doO * Fc);
    oO[0] = make_float4(accO[0], accO[1], accO[2], accO[3]);
    oO[1] = make_float4(accO[4], accO[5], accO[6], accO[7]);
}

extern "C" void kernel_launch(void* const* d_in, const int* in_sizes, int n_in,
                              void* d_out, int out_size, void* d_ws, size_t ws_size,
                              hipStream_t stream) {
    const float* images     = (const float*)d_in[0];
    const int*   base_plane = (const int*)d_in[1];
    const float* kern       = (const float*)d_in[2];
    // d_in[3] = default_value, frozen zero per reference docstring
    float* out = (float*)d_out;

    dim3 grid(WoC / 8, HoC, Bc);   // 16 x 128 x 2 = 4096 blocks
    dim3 block(256);
    hipLaunchKernelGGL(sconv3dt_kernel, grid, block, 0, stream,
                       images, base_plane, kern, out);
}